// Round 5
// baseline (516.673 us; speedup 1.0000x reference)
//
#include <hip/hip_runtime.h>

// Problem constants
#define B_  64
#define S_  512
#define D_  768
#define H_  768
#define C_  5
#define M_  (B_ * S_)        // 32768 rows

typedef float f32x4 __attribute__((ext_vector_type(4)));
typedef short short8 __attribute__((ext_vector_type(8)));   // bf16x8 MFMA operand

#define W1T_ELEMS (D_ * H_)      // 589824  (bf16: 1.18 MB)
#define XBF_ELEMS (M_ * D_)      // 25165824 (bf16: 50.33 MB)

// prep_all grid partition
#define PX_BLOCKS   (XBF_ELEMS / (256 * 8))          // 12288
#define PW_BLOCKS   ((D_ / 32) * (H_ / 32))          // 576
#define PI_BLOCKS   ((M_ * C_ + 255) / 256)          // 640

__device__ __forceinline__ unsigned short f2bf(float f) {
    unsigned int u = __float_as_uint(f);
    u += 0x7FFFu + ((u >> 16) & 1u);     // RNE
    return (unsigned short)(u >> 16);
}

__device__ __forceinline__ void gload16(const void* g, void* l) {
    __builtin_amdgcn_global_load_lds(
        (const __attribute__((address_space(1))) unsigned int*)g,
        (__attribute__((address_space(3))) unsigned int*)l, 16, 0, 0);
}

// =========================================================================
// Kernel 1: fused prep — prep_x | prep_w1 | init_pot in one dispatch
// (proven R0 kernel, ~38 us, HBM-bound)
// =========================================================================
__global__ __launch_bounds__(256) void prep_all_kernel(
    const float* __restrict__ X, const float* __restrict__ W1,
    const float* __restrict__ b2, const float* __restrict__ lb,
    const float* __restrict__ rb,
    unsigned short* __restrict__ xbf, unsigned short* __restrict__ w1t,
    float* __restrict__ pot)
{
    __shared__ float t[32][33];
    const int bid = blockIdx.x;
    const int tid = threadIdx.x;

    if (bid < PX_BLOCKS) {
        // ---- X fp32 -> bf16 ----
        const size_t i0 = ((size_t)bid * 256 + tid) * 8;
        const float4 a = *(const float4*)(X + i0);
        const float4 b = *(const float4*)(X + i0 + 4);
        union { unsigned short u[8]; uint4 v; } o;
        o.u[0] = f2bf(a.x); o.u[1] = f2bf(a.y); o.u[2] = f2bf(a.z); o.u[3] = f2bf(a.w);
        o.u[4] = f2bf(b.x); o.u[5] = f2bf(b.y); o.u[6] = f2bf(b.z); o.u[7] = f2bf(b.w);
        *(uint4*)(xbf + i0) = o.v;
    } else if (bid < PX_BLOCKS + PW_BLOCKS) {
        // ---- W1 [k][n] fp32 -> w1t [n][k] bf16 (LDS-tiled transpose) ----
        const int b2i = bid - PX_BLOCKS;
        const int bx = b2i % (H_ / 32);       // n tile
        const int by = b2i / (H_ / 32);       // k tile
        const int lx = tid & 31, ly = tid >> 5;
        #pragma unroll
        for (int j = 0; j < 4; ++j)
            t[ly + 8 * j][lx] = W1[(by * 32 + ly + 8 * j) * H_ + bx * 32 + lx];
        __syncthreads();
        #pragma unroll
        for (int j = 0; j < 4; ++j)
            w1t[(size_t)(bx * 32 + ly + 8 * j) * D_ + by * 32 + lx] = f2bf(t[lx][ly + 8 * j]);
    } else {
        // ---- pot = b2 + boundaries ----
        const int idx = (bid - PX_BLOCKS - PW_BLOCKS) * 256 + tid;
        if (idx < M_ * C_) {
            const int c = idx % C_;
            const int tt = (idx / C_) & (S_ - 1);
            float v = b2[c];
            if (tt == 0)      v += lb[c];
            if (tt == S_ - 1) v += rb[c];
            pot[idx] = v;
        }
    }
}

__global__ __launch_bounds__(256) void init_pot_kernel(
    const float* __restrict__ b2, const float* __restrict__ lb,
    const float* __restrict__ rb, float* __restrict__ pot)
{
    const int idx = blockIdx.x * 256 + threadIdx.x;
    if (idx < M_ * C_) {
        const int c = idx % C_;
        const int t = (idx / C_) & (S_ - 1);
        float v = b2[c];
        if (t == 0)      v += lb[c];
        if (t == S_ - 1) v += rb[c];
        pot[idx] = v;
    }
}

// =========================================================================
// Kernel 2 (R4 redesign, typo-fixed): B-resident-in-LDS, barrier-free loop.
//
// R0-R3 invariant: staging rate pinned at ~9-10 B/cy/CU because every
// K-step pays a full memory-latency drain at a barrier (12-iter K-loop
// never amortizes it). Fix: eliminate repeated staging. B-slice for
// 96 cols x full K=768 = 144 KB -> stage into LDS ONCE, one barrier,
// then a pure-compute loop: A (xbf bf16) straight into registers (24
// independent short8 loads per half-K, imm-offset addressable), B frags
// from read-only LDS (mi=2 reg reuse => 32 FLOP/LDS-byte), no barriers,
// no LDS writes, waves fully independent -> ILP + 2 waves/SIMD hide all
// latency. Grid 256 = 8 n-slices x 32 m-groups (1 block/CU, exact).
// XCD: ns = bid>>5, mgrp = bid&31 -> the 8 n-siblings of an m-group all
// have bid % 8 == mgrp % 8 => same XCD => A-chunk L2 reuse x8.
// Per block: 1024 rows = 4 chunks x (8 waves x 32 rows). Epilogue per
// chunk: relu(h+b1)@W2 partials, shfl-reduce over i15, 4 lanes/wave
// atomicAdd into pre-initialized pot (8 slices accumulate).
// =========================================================================
#define NS_   8            // n-slices
#define NCOL_ 96           // cols per slice
#define KF_   (D_ / 32)    // 24 k-fragments

__global__ __launch_bounds__(512, 2) void gemm_nres_kernel(
    const unsigned short* __restrict__ xbf,   // [M_, D_] bf16
    const unsigned short* __restrict__ w1t,   // [H_, D_] bf16 (n-major)
    const float* __restrict__ b1,
    const float* __restrict__ W2,             // [H_, C_]
    float* __restrict__ pot)                  // [M_, C_] pre-initialized
{
    // B slab: [24 kf][6 g][512 shorts] ; 512 = 16 cols x 32 k
    __shared__ __align__(16) unsigned short Blds[KF_ * 6 * 512];   // 147456 B
    __shared__ float W2s[NCOL_ * C_];                              // 1920 B
    __shared__ float B1s[NCOL_];                                   // 384 B

    const int tid  = threadIdx.x;
    const int lane = tid & 63, w = tid >> 6;       // wave 0..7
    const int i15  = lane & 15, quad = lane >> 4;

    const int bid  = blockIdx.x;
    const int ns   = bid >> 5;          // n-slice 0..7
    const int mgrp = bid & 31;          // m-group 0..31
    const int n0   = ns * NCOL_;

    // ---- one-time staging: B slab (144 x gload16), W2/b1 slices ----
    #pragma unroll
    for (int j = 0; j < 18; ++j) {
        const int idx = w * 18 + j;            // 0..143
        const int kf = idx / 6, g = idx % 6;
        const unsigned short* src =
            w1t + (size_t)(n0 + g * 16 + i15) * D_ + kf * 32 + quad * 8;
        gload16(src, &Blds[idx * 512]);
    }
    if (tid < NCOL_ * C_) W2s[tid] = W2[(n0 + tid / C_) * C_ + tid % C_];
    else if (tid < NCOL_ * C_ + NCOL_) B1s[tid - NCOL_ * C_] = b1[n0 + tid - NCOL_ * C_];
    __syncthreads();   // drains vmcnt(0): B slab + W2s/B1s visible. LAST barrier.

    // ---- 4 chunks of 256 rows; wave owns 32 rows ----
    for (int c = 0; c < 4; ++c) {
        const int rowb = mgrp * 1024 + c * 256 + w * 32;

        f32x4 acc[2][6];
        #pragma unroll
        for (int mi = 0; mi < 2; ++mi)
            #pragma unroll
            for (int ni = 0; ni < 6; ++ni)
                acc[mi][ni] = (f32x4){0.f, 0.f, 0.f, 0.f};

        const unsigned short* aRow0 = xbf + (size_t)(rowb + i15)      * D_ + quad * 8;
        const unsigned short* aRow1 = xbf + (size_t)(rowb + 16 + i15) * D_ + quad * 8;

        #pragma unroll
        for (int h = 0; h < 2; ++h) {
            // 24 independent A-frag loads (imm offsets off two base ptrs)
            short8 af[2][12];
            #pragma unroll
            for (int kf = 0; kf < 12; ++kf) {
                af[0][kf] = *(const short8*)(aRow0 + h * 384 + kf * 32);
                af[1][kf] = *(const short8*)(aRow1 + h * 384 + kf * 32);
            }
            #pragma unroll
            for (int kf = 0; kf < 12; ++kf) {
                short8 bfr[6];
                #pragma unroll
                for (int ni = 0; ni < 6; ++ni)
                    bfr[ni] = *(const short8*)
                        &Blds[((h * 12 + kf) * 6 + ni) * 512 + lane * 8];
                #pragma unroll
                for (int ni = 0; ni < 6; ++ni)
                    #pragma unroll
                    for (int mi = 0; mi < 2; ++mi)
                        acc[mi][ni] = __builtin_amdgcn_mfma_f32_16x16x32_bf16(
                            af[mi][kf], bfr[ni], acc[mi][ni], 0, 0, 0);
            }
        }

        // ---- epilogue: relu(h+b1)@W2 partials -> shfl-reduce -> atomics ----
        #pragma unroll
        for (int mi = 0; mi < 2; ++mi) {
            float ps[4][C_];
            #pragma unroll
            for (int r = 0; r < 4; ++r)
                #pragma unroll
                for (int cc = 0; cc < C_; ++cc) ps[r][cc] = 0.f;

            #pragma unroll
            for (int ni = 0; ni < 6; ++ni) {
                const int colL = ni * 16 + i15;
                const float b1v = B1s[colL];
                float w2v[C_];
                #pragma unroll
                for (int cc = 0; cc < C_; ++cc) w2v[cc] = W2s[colL * C_ + cc];
                #pragma unroll
                for (int r = 0; r < 4; ++r) {
                    float hh = acc[mi][ni][r] + b1v;
                    hh = hh > 0.f ? hh : 0.f;
                    #pragma unroll
                    for (int cc = 0; cc < C_; ++cc)
                        ps[r][cc] = fmaf(hh, w2v[cc], ps[r][cc]);
                }
            }

            #pragma unroll
            for (int off = 1; off < 16; off <<= 1)
                #pragma unroll
                for (int r = 0; r < 4; ++r)
                    #pragma unroll
                    for (int cc = 0; cc < C_; ++cc)
                        ps[r][cc] += __shfl_xor(ps[r][cc], off, 64);

            if (i15 == 0) {
                #pragma unroll
                for (int r = 0; r < 4; ++r) {
                    const int row = rowb + mi * 16 + quad * 4 + r;
                    #pragma unroll
                    for (int cc = 0; cc < C_; ++cc)
                        atomicAdd(&pot[(size_t)row * C_ + cc], ps[r][cc]);
                }
            }
        }
    }
}

// =========================================================================
// Last-resort fp32 GEMM (proven) if ws too small for xbf+w1t
// =========================================================================
#define FBK 8
#define FLDS 132
__global__ __launch_bounds__(256) void gemm_relu_pot_kernel(
    const float* __restrict__ X, const float* __restrict__ W1,
    const float* __restrict__ b1, const float* __restrict__ W2,
    float* __restrict__ pot)
{
    __shared__ float As[FBK * FLDS];
    __shared__ float Bs[FBK * FLDS];
    __shared__ float w2s[128][C_];

    const int tid = threadIdx.x;
    const int tx = tid & 15, ty = tid >> 4;
    const int m0 = blockIdx.y * 128, n0 = blockIdx.x * 128;

    for (int idx = tid; idx < 128 * C_; idx += 256)
        w2s[idx / C_][idx % C_] = W2[(n0 + idx / C_) * C_ + idx % C_];

    float acc[2][2][4][4];
    #pragma unroll
    for (int a = 0; a < 2; ++a)
        #pragma unroll
        for (int b = 0; b < 2; ++b)
            #pragma unroll
            for (int i = 0; i < 4; ++i)
                #pragma unroll
                for (int j = 0; j < 4; ++j) acc[a][b][i][j] = 0.f;

    const int arow = tid >> 1, aq = tid & 1;
    const int brow = tid >> 5, bq = tid & 31;
    const float* Aptr = X + (m0 + arow) * D_ + aq * 4;
    const float* Bptr = W1 + brow * H_ + n0 + bq * 4;

    for (int kt = 0; kt < D_; kt += FBK) {
        const float4 avv = *(const float4*)Aptr;
        const float4 bvv = *(const float4*)Bptr;
        __syncthreads();
        As[(aq * 4 + 0) * FLDS + arow] = avv.x;
        As[(aq * 4 + 1) * FLDS + arow] = avv.y;
        As[(aq * 4 + 2) * FLDS + arow] = avv.z;
        As[(aq * 4 + 3) * FLDS + arow] = avv.w;
        *(float4*)&Bs[brow * FLDS + bq * 4] = bvv;
        __syncthreads();
        #pragma unroll
        for (int k = 0; k < FBK; ++k) {
            const float4 a0 = *(const float4*)&As[k * FLDS + (ty << 2)];
            const float4 a1 = *(const float4*)&As[k * FLDS + 64 + (ty << 2)];
            const float4 b0 = *(const float4*)&Bs[k * FLDS + (tx << 2)];
            const float4 b1r = *(const float4*)&Bs[k * FLDS + 64 + (tx << 2)];
            const float ar[2][4] = {{a0.x,a0.y,a0.z,a0.w},{a1.x,a1.y,a1.z,a1.w}};
            const float br[2][4] = {{b0.x,b0.y,b0.z,b0.w},{b1r.x,b1r.y,b1r.z,b1r.w}};
            #pragma unroll
            for (int ri = 0; ri < 2; ++ri)
                #pragma unroll
                for (int i = 0; i < 4; ++i)
                    #pragma unroll
                    for (int rj = 0; rj < 2; ++rj)
                        #pragma unroll
                        for (int j = 0; j < 4; ++j)
                            acc[ri][rj][i][j] = fmaf(ar[ri][i], br[rj][j], acc[ri][rj][i][j]);
        }
        Aptr += FBK;
        Bptr += FBK * H_;
    }

    float ps[2][4][C_];
    #pragma unroll
    for (int ri = 0; ri < 2; ++ri)
        #pragma unroll
        for (int i = 0; i < 4; ++i)
            #pragma unroll
            for (int cc = 0; cc < C_; ++cc) ps[ri][i][cc] = 0.f;

    #pragma unroll
    for (int rj = 0; rj < 2; ++rj)
        #pragma unroll
        for (int j = 0; j < 4; ++j) {
            const int nl = rj * 64 + (tx << 2) + j;
            const float bj = b1[n0 + nl];
            float w2c[C_];
            #pragma unroll
            for (int cc = 0; cc < C_; ++cc) w2c[cc] = w2s[nl][cc];
            #pragma unroll
            for (int ri = 0; ri < 2; ++ri)
                #pragma unroll
                for (int i = 0; i < 4; ++i) {
                    float h = acc[ri][rj][i][j] + bj;
                    h = h > 0.f ? h : 0.f;
                    #pragma unroll
                    for (int cc = 0; cc < C_; ++cc)
                        ps[ri][i][cc] = fmaf(h, w2c[cc], ps[ri][i][cc]);
                }
        }

    #pragma unroll
    for (int off = 1; off < 16; off <<= 1)
        #pragma unroll
        for (int ri = 0; ri < 2; ++ri)
            #pragma unroll
            for (int i = 0; i < 4; ++i)
                #pragma unroll
                for (int cc = 0; cc < C_; ++cc)
                    ps[ri][i][cc] += __shfl_xor(ps[ri][i][cc], off, 64);

    if (tx == 0)
        #pragma unroll
        for (int ri = 0; ri < 2; ++ri)
            #pragma unroll
            for (int i = 0; i < 4; ++i) {
                const int m = m0 + ri * 64 + (ty << 2) + i;
                #pragma unroll
                for (int cc = 0; cc < C_; ++cc)
                    atomicAdd(&pot[m * C_ + cc], ps[ri][i][cc]);
            }
}

// =========================================================================
// Kernel 3: Viterbi via max-plus associative scan (verified).
// =========================================================================
__global__ __launch_bounds__(64) void viterbi_kernel(
    const float* __restrict__ pot, const float* __restrict__ trans,
    const int* __restrict__ mask, float* __restrict__ decoded,
    float* __restrict__ seqlen, float* __restrict__ chain_out)
{
    const int b = blockIdx.x;
    const int lane = threadIdx.x;

    __shared__ float pl[S_ * C_];
    __shared__ unsigned int bpk[S_];
    __shared__ unsigned int gseg[64];
    __shared__ int bt[64];
    __shared__ int dec_s[S_];
    __shared__ int s_last;

    const float* pb = pot + b * (S_ * C_);
    for (int i = lane; i < S_ * C_; i += 64) pl[i] = pb[i];

    int mcnt = 0;
    const int* mb = mask + b * S_;
    for (int i = lane; i < S_; i += 64) mcnt += (mb[i] != 0) ? 1 : 0;
    #pragma unroll
    for (int off = 32; off >= 1; off >>= 1) mcnt += __shfl_xor(mcnt, off, 64);

    if (b == 0 && lane < C_ * C_) chain_out[lane] = trans[lane];

    float tr[C_][C_];
    #pragma unroll
    for (int p = 0; p < C_; ++p)
        #pragma unroll
        for (int c = 0; c < C_; ++c) tr[p][c] = trans[p * C_ + c];

    __syncthreads();

    const float NEG = -1.0e30f;

    float G[C_][C_];
    #pragma unroll
    for (int c = 0; c < C_; ++c)
        #pragma unroll
        for (int p = 0; p < C_; ++p) G[c][p] = (c == p) ? 0.f : NEG;

    for (int j = 1; j <= 8; ++j) {
        const int t = 8 * lane + j;
        if (t < S_) {
            float ng[C_][C_];
            #pragma unroll
            for (int c = 0; c < C_; ++c) {
                const float pc = pl[t * C_ + c];
                #pragma unroll
                for (int p = 0; p < C_; ++p) {
                    float m = tr[0][c] + G[0][p];
                    #pragma unroll
                    for (int q = 1; q < C_; ++q)
                        m = fmaxf(m, tr[q][c] + G[q][p]);
                    ng[c][p] = m + pc;
                }
            }
            #pragma unroll
            for (int c = 0; c < C_; ++c)
                #pragma unroll
                for (int p = 0; p < C_; ++p) G[c][p] = ng[c][p];
        }
    }

    #pragma unroll
    for (int d = 1; d < 64; d <<= 1) {
        float Q[C_][C_];
        #pragma unroll
        for (int q = 0; q < C_; ++q)
            #pragma unroll
            for (int p = 0; p < C_; ++p) Q[q][p] = __shfl_up(G[q][p], d, 64);
        if (lane >= d) {
            float ng[C_][C_];
            #pragma unroll
            for (int c = 0; c < C_; ++c)
                #pragma unroll
                for (int p = 0; p < C_; ++p) {
                    float m = G[c][0] + Q[0][p];
                    #pragma unroll
                    for (int q = 1; q < C_; ++q)
                        m = fmaxf(m, G[c][q] + Q[q][p]);
                    ng[c][p] = m;
                }
            #pragma unroll
            for (int c = 0; c < C_; ++c)
                #pragma unroll
                for (int p = 0; p < C_; ++p) G[c][p] = ng[c][p];
        }
    }

    float a[C_];
    {
        float E[C_][C_];
        #pragma unroll
        for (int c = 0; c < C_; ++c)
            #pragma unroll
            for (int p = 0; p < C_; ++p) E[c][p] = __shfl_up(G[c][p], 1, 64);
        float a0[C_];
        #pragma unroll
        for (int c = 0; c < C_; ++c) a0[c] = pl[c];
        if (lane == 0) {
            #pragma unroll
            for (int c = 0; c < C_; ++c) a[c] = a0[c];
        } else {
            #pragma unroll
            for (int c = 0; c < C_; ++c) {
                float m = E[c][0] + a0[0];
                #pragma unroll
                for (int q = 1; q < C_; ++q) m = fmaxf(m, E[c][q] + a0[q]);
                a[c] = m;
            }
        }
    }

    for (int j = 1; j <= 8; ++j) {
        const int t = 8 * lane + j;
        if (t < S_) {
            unsigned int mpack = 0;
            float na[C_];
            #pragma unroll
            for (int c = 0; c < C_; ++c) {
                float best = a[0] + tr[0][c];
                int arg = 0;
                #pragma unroll
                for (int p = 1; p < C_; ++p) {
                    const float s = a[p] + tr[p][c];
                    if (s > best) { best = s; arg = p; }
                }
                mpack |= (unsigned int)arg << (3 * c);
                na[c] = best + pl[t * C_ + c];
            }
            bpk[t] = mpack;
            #pragma unroll
            for (int c = 0; c < C_; ++c) a[c] = na[c];
        }
    }

    if (lane == 63) {
        float best = a[0];
        int arg = 0;
        #pragma unroll
        for (int p = 1; p < C_; ++p)
            if (a[p] > best) { best = a[p]; arg = p; }
        s_last = arg;
    }
    if (lane == 0) bpk[0] = 0;
    __syncthreads();

    const int last = s_last;

    unsigned int g = 0u | (1u << 3) | (2u << 6) | (3u << 9) | (4u << 12);
    #pragma unroll
    for (int j = 7; j >= 0; --j) {
        const int t = 8 * lane + j;
        if (t >= 1) {
            const unsigned int m = bpk[t];
            unsigned int ng = 0;
            #pragma unroll
            for (int x = 0; x < C_; ++x) {
                const unsigned int gx = (g >> (3 * x)) & 7u;
                ng |= ((m >> (3 * gx)) & 7u) << (3 * x);
            }
            g = ng;
        }
    }
    gseg[lane] = g;
    __syncthreads();

    if (lane == 0) {
        int cur = last;
        for (int l = 63; l >= 0; --l) {
            bt[l] = cur;
            cur = (int)((gseg[l] >> (3 * cur)) & 7u);
        }
        seqlen[b] = (float)mcnt;
    }
    __syncthreads();

    {
        int tag = bt[lane];
        const int t0 = 8 * lane;
        dec_s[t0 + 7] = tag;
        #pragma unroll
        for (int t = t0 + 7; t >= t0 + 1; --t) {
            tag = (int)((bpk[t] >> (3 * tag)) & 7u);
            dec_s[t - 1] = tag;
        }
    }
    __syncthreads();

    float* db = decoded + b * S_;
    for (int i = lane; i < S_; i += 64) db[i] = (float)dec_s[i];
}

// =========================================================================
extern "C" void kernel_launch(void* const* d_in, const int* in_sizes, int n_in,
                              void* d_out, int out_size, void* d_ws, size_t ws_size,
                              hipStream_t stream) {
    const float* hs    = (const float*)d_in[0];
    const int*   mask  = (const int*)  d_in[1];
    const float* W1    = (const float*)d_in[2];
    const float* b1    = (const float*)d_in[3];
    const float* W2    = (const float*)d_in[4];
    const float* b2    = (const float*)d_in[5];
    const float* chain = (const float*)d_in[6];
    const float* lb    = (const float*)d_in[7];
    const float* rb    = (const float*)d_in[8];

    float* out      = (float*)d_out;
    float* decoded  = out;
    float* pot      = out + M_;
    float* seq      = out + M_ + M_ * C_;
    float* chainout = seq + B_;

    const size_t need_all = (size_t)W1T_ELEMS * sizeof(unsigned short)
                          + (size_t)XBF_ELEMS * sizeof(unsigned short);   // 51.5 MB

    if (ws_size >= need_all) {
        unsigned short* w1t = (unsigned short*)d_ws;
        unsigned short* xbf = w1t + W1T_ELEMS;
        prep_all_kernel<<<PX_BLOCKS + PW_BLOCKS + PI_BLOCKS, 256, 0, stream>>>(
            hs, W1, b2, lb, rb, xbf, w1t, pot);
        gemm_nres_kernel<<<256, 512, 0, stream>>>(xbf, w1t, b1, W2, pot);
    } else {
        init_pot_kernel<<<PI_BLOCKS, 256, 0, stream>>>(b2, lb, rb, pot);
        dim3 grid(H_ / 128, M_ / 128);
        gemm_relu_pot_kernel<<<grid, 256, 0, stream>>>(hs, W1, b1, W2, pot);
    }

    viterbi_kernel<<<B_, 64, 0, stream>>>(pot, chain, mask, decoded, seq, chainout);
}

// Round 7
// 489.486 us; speedup vs baseline: 1.0555x; 1.0555x over previous
//
#include <hip/hip_runtime.h>

// Problem constants
#define B_  64
#define S_  512
#define D_  768
#define H_  768
#define C_  5
#define M_  (B_ * S_)        // 32768 rows

typedef float f32x4 __attribute__((ext_vector_type(4)));
typedef short short8 __attribute__((ext_vector_type(8)));   // bf16x8 MFMA operand

#define W1T_ELEMS (D_ * H_)      // 589824  (bf16: 1.18 MB)
#define XBF_ELEMS (M_ * D_)      // 25165824 (bf16: 50.33 MB)
#define NS_   8                  // n-slices
#define NCOL_ 96                 // cols per slice
#define KF_   (D_ / 32)          // 24 k-fragments
#define PART_ELEMS (NS_ * M_ * C_)   // 1310720 floats = 5.24 MB

// prep_all grid partition
#define PX_BLOCKS   (XBF_ELEMS / (256 * 8))          // 12288
#define PW_BLOCKS   ((D_ / 32) * (H_ / 32))          // 576

__device__ __forceinline__ unsigned short f2bf(float f) {
    unsigned int u = __float_as_uint(f);
    u += 0x7FFFu + ((u >> 16) & 1u);     // RNE
    return (unsigned short)(u >> 16);
}

__device__ __forceinline__ void gload16(const void* g, void* l) {
    __builtin_amdgcn_global_load_lds(
        (const __attribute__((address_space(1))) unsigned int*)g,
        (__attribute__((address_space(3))) unsigned int*)l, 16, 0, 0);
}

// =========================================================================
// Kernel 1: fused prep — prep_x | prep_w1
// =========================================================================
__global__ __launch_bounds__(256) void prep_all_kernel(
    const float* __restrict__ X, const float* __restrict__ W1,
    unsigned short* __restrict__ xbf, unsigned short* __restrict__ w1t)
{
    __shared__ float t[32][33];
    const int bid = blockIdx.x;
    const int tid = threadIdx.x;

    if (bid < PX_BLOCKS) {
        // ---- X fp32 -> bf16 ----
        const size_t i0 = ((size_t)bid * 256 + tid) * 8;
        const float4 a = *(const float4*)(X + i0);
        const float4 b = *(const float4*)(X + i0 + 4);
        union { unsigned short u[8]; uint4 v; } o;
        o.u[0] = f2bf(a.x); o.u[1] = f2bf(a.y); o.u[2] = f2bf(a.z); o.u[3] = f2bf(a.w);
        o.u[4] = f2bf(b.x); o.u[5] = f2bf(b.y); o.u[6] = f2bf(b.z); o.u[7] = f2bf(b.w);
        *(uint4*)(xbf + i0) = o.v;
    } else {
        // ---- W1 [k][n] fp32 -> w1t [n][k] bf16 (LDS-tiled transpose) ----
        const int b2i = bid - PX_BLOCKS;
        const int bx = b2i % (H_ / 32);       // n tile
        const int by = b2i / (H_ / 32);       // k tile
        const int lx = tid & 31, ly = tid >> 5;
        #pragma unroll
        for (int j = 0; j < 4; ++j)
            t[ly + 8 * j][lx] = W1[(by * 32 + ly + 8 * j) * H_ + bx * 32 + lx];
        __syncthreads();
        #pragma unroll
        for (int j = 0; j < 4; ++j)
            w1t[(size_t)(bx * 32 + ly + 8 * j) * D_ + by * 32 + lx] = f2bf(t[lx][ly + 8 * j]);
    }
}

__global__ __launch_bounds__(256) void init_pot_kernel(
    const float* __restrict__ b2, const float* __restrict__ lb,
    const float* __restrict__ rb, float* __restrict__ pot)
{
    const int idx = blockIdx.x * 256 + threadIdx.x;
    if (idx < M_ * C_) {
        const int c = idx % C_;
        const int t = (idx / C_) & (S_ - 1);
        float v = b2[c];
        if (t == 0)      v += lb[c];
        if (t == S_ - 1) v += rb[c];
        pot[idx] = v;
    }
}

// =========================================================================
// Kernel 2 (R7): R5/R6 structure with the B1s staging bug FIXED.
//
// R6 post-mortem: `else if (tid < 480+96)` never ran for tid in [512,576)
// -> B1s[32..95] read stale LDS (b1==0 in-problem, so R5 passed only
// because that LDS residue happened to be zero on that node). Fixed with
// two independent guarded loads. Template ATOMIC selects epilogue:
//   false: plain stores to part[ns][row][C] (reduce kernel sums)  [main]
//   true : atomicAdd into pre-initialized pot                     [mid ws]
// Everything else identical: B slab 96 cols x K=768 resident in LDS,
// one barrier, barrier-free compute loop, A (xbf) straight to registers.
// =========================================================================
template<bool ATOMIC>
__global__ __launch_bounds__(512, 2) void gemm_nres_t(
    const unsigned short* __restrict__ xbf,   // [M_, D_] bf16
    const unsigned short* __restrict__ w1t,   // [H_, D_] bf16 (n-major)
    const float* __restrict__ b1,
    const float* __restrict__ W2,             // [H_, C_]
    float* __restrict__ outp)                 // part (ATOMIC=0) | pot (ATOMIC=1)
{
    // B slab: [24 kf][6 g][512 shorts] ; 512 = 16 cols x 32 k
    __shared__ __align__(16) unsigned short Blds[KF_ * 6 * 512];   // 147456 B
    __shared__ float W2s[NCOL_ * C_];                              // 1920 B
    __shared__ float B1s[NCOL_];                                   // 384 B

    const int tid  = threadIdx.x;
    const int lane = tid & 63, w = tid >> 6;       // wave 0..7
    const int i15  = lane & 15, quad = lane >> 4;

    const int bid  = blockIdx.x;
    const int ns   = bid >> 5;          // n-slice 0..7
    const int mgrp = bid & 31;          // m-group 0..31
    const int n0   = ns * NCOL_;

    // ---- one-time staging: B slab (144 x gload16), W2/b1 slices ----
    #pragma unroll
    for (int j = 0; j < 18; ++j) {
        const int idx = w * 18 + j;            // 0..143
        const int kf = idx / 6, g = idx % 6;
        const unsigned short* src =
            w1t + (size_t)(n0 + g * 16 + i15) * D_ + kf * 32 + quad * 8;
        gload16(src, &Blds[idx * 512]);
    }
    if (tid < NCOL_ * C_) W2s[tid] = W2[(n0 + tid / C_) * C_ + tid % C_];
    if (tid < NCOL_)      B1s[tid] = b1[n0 + tid];          // FIX: full 96 loaded
    __syncthreads();   // drains vmcnt(0): B slab + W2s/B1s visible. LAST barrier.

    // ---- 4 chunks of 256 rows; wave owns 32 rows ----
    for (int c = 0; c < 4; ++c) {
        const int rowb = mgrp * 1024 + c * 256 + w * 32;

        f32x4 acc[2][6];
        #pragma unroll
        for (int mi = 0; mi < 2; ++mi)
            #pragma unroll
            for (int ni = 0; ni < 6; ++ni)
                acc[mi][ni] = (f32x4){0.f, 0.f, 0.f, 0.f};

        const unsigned short* aRow0 = xbf + (size_t)(rowb + i15)      * D_ + quad * 8;
        const unsigned short* aRow1 = xbf + (size_t)(rowb + 16 + i15) * D_ + quad * 8;

        #pragma unroll
        for (int h = 0; h < 2; ++h) {
            // 24 independent A-frag loads (imm offsets off two base ptrs)
            short8 af[2][12];
            #pragma unroll
            for (int kf = 0; kf < 12; ++kf) {
                af[0][kf] = *(const short8*)(aRow0 + h * 384 + kf * 32);
                af[1][kf] = *(const short8*)(aRow1 + h * 384 + kf * 32);
            }
            #pragma unroll
            for (int kf = 0; kf < 12; ++kf) {
                short8 bfr[6];
                #pragma unroll
                for (int ni = 0; ni < 6; ++ni)
                    bfr[ni] = *(const short8*)
                        &Blds[((h * 12 + kf) * 6 + ni) * 512 + lane * 8];
                #pragma unroll
                for (int ni = 0; ni < 6; ++ni)
                    #pragma unroll
                    for (int mi = 0; mi < 2; ++mi)
                        acc[mi][ni] = __builtin_amdgcn_mfma_f32_16x16x32_bf16(
                            af[mi][kf], bfr[ni], acc[mi][ni], 0, 0, 0);
            }
        }

        // ---- epilogue: relu(h+b1)@W2 partials -> shfl-reduce -> out ----
        #pragma unroll
        for (int mi = 0; mi < 2; ++mi) {
            float ps[4][C_];
            #pragma unroll
            for (int r = 0; r < 4; ++r)
                #pragma unroll
                for (int cc = 0; cc < C_; ++cc) ps[r][cc] = 0.f;

            #pragma unroll
            for (int ni = 0; ni < 6; ++ni) {
                const int colL = ni * 16 + i15;
                const float b1v = B1s[colL];
                float w2v[C_];
                #pragma unroll
                for (int cc = 0; cc < C_; ++cc) w2v[cc] = W2s[colL * C_ + cc];
                #pragma unroll
                for (int r = 0; r < 4; ++r) {
                    float hh = acc[mi][ni][r] + b1v;
                    hh = hh > 0.f ? hh : 0.f;
                    #pragma unroll
                    for (int cc = 0; cc < C_; ++cc)
                        ps[r][cc] = fmaf(hh, w2v[cc], ps[r][cc]);
                }
            }

            #pragma unroll
            for (int off = 1; off < 16; off <<= 1)
                #pragma unroll
                for (int r = 0; r < 4; ++r)
                    #pragma unroll
                    for (int cc = 0; cc < C_; ++cc)
                        ps[r][cc] += __shfl_xor(ps[r][cc], off, 64);

            if (i15 == 0) {
                #pragma unroll
                for (int r = 0; r < 4; ++r) {
                    const int row = rowb + mi * 16 + quad * 4 + r;
                    #pragma unroll
                    for (int cc = 0; cc < C_; ++cc) {
                        if (ATOMIC)
                            atomicAdd(&outp[(size_t)row * C_ + cc], ps[r][cc]);
                        else
                            outp[((size_t)ns * M_ + row) * C_ + cc] = ps[r][cc];
                    }
                }
            }
        }
    }
}

// =========================================================================
// Kernel 2b: reduce partials + b2/boundaries -> pot
// =========================================================================
__global__ __launch_bounds__(256) void reduce_pot_kernel(
    const float* __restrict__ part, const float* __restrict__ b2,
    const float* __restrict__ lb, const float* __restrict__ rb,
    float* __restrict__ pot)
{
    const int idx = blockIdx.x * 256 + threadIdx.x;
    if (idx < M_ * C_) {
        const int c = idx % C_;
        const int t = (idx / C_) & (S_ - 1);
        float v = b2[c];
        if (t == 0)      v += lb[c];
        if (t == S_ - 1) v += rb[c];
        #pragma unroll
        for (int ns = 0; ns < NS_; ++ns)
            v += part[(size_t)ns * (M_ * C_) + idx];
        pot[idx] = v;
    }
}

// =========================================================================
// Last-resort fp32 GEMM if ws too small
// =========================================================================
#define FBK 8
#define FLDS 132
__global__ __launch_bounds__(256) void gemm_relu_pot_kernel(
    const float* __restrict__ X, const float* __restrict__ W1,
    const float* __restrict__ b1, const float* __restrict__ W2,
    float* __restrict__ pot)
{
    __shared__ float As[FBK * FLDS];
    __shared__ float Bs[FBK * FLDS];
    __shared__ float w2s[128][C_];

    const int tid = threadIdx.x;
    const int tx = tid & 15, ty = tid >> 4;
    const int m0 = blockIdx.y * 128, n0 = blockIdx.x * 128;

    for (int idx = tid; idx < 128 * C_; idx += 256)
        w2s[idx / C_][idx % C_] = W2[(n0 + idx / C_) * C_ + idx % C_];

    float acc[2][2][4][4];
    #pragma unroll
    for (int a = 0; a < 2; ++a)
        #pragma unroll
        for (int b = 0; b < 2; ++b)
            #pragma unroll
            for (int i = 0; i < 4; ++i)
                #pragma unroll
                for (int j = 0; j < 4; ++j) acc[a][b][i][j] = 0.f;

    const int arow = tid >> 1, aq = tid & 1;
    const int brow = tid >> 5, bq = tid & 31;
    const float* Aptr = X + (m0 + arow) * D_ + aq * 4;
    const float* Bptr = W1 + brow * H_ + n0 + bq * 4;

    for (int kt = 0; kt < D_; kt += FBK) {
        const float4 avv = *(const float4*)Aptr;
        const float4 bvv = *(const float4*)Bptr;
        __syncthreads();
        As[(aq * 4 + 0) * FLDS + arow] = avv.x;
        As[(aq * 4 + 1) * FLDS + arow] = avv.y;
        As[(aq * 4 + 2) * FLDS + arow] = avv.z;
        As[(aq * 4 + 3) * FLDS + arow] = avv.w;
        *(float4*)&Bs[brow * FLDS + bq * 4] = bvv;
        __syncthreads();
        #pragma unroll
        for (int k = 0; k < FBK; ++k) {
            const float4 a0 = *(const float4*)&As[k * FLDS + (ty << 2)];
            const float4 a1 = *(const float4*)&As[k * FLDS + 64 + (ty << 2)];
            const float4 b0 = *(const float4*)&Bs[k * FLDS + (tx << 2)];
            const float4 b1r = *(const float4*)&Bs[k * FLDS + 64 + (tx << 2)];
            const float ar[2][4] = {{a0.x,a0.y,a0.z,a0.w},{a1.x,a1.y,a1.z,a1.w}};
            const float br[2][4] = {{b0.x,b0.y,b0.z,b0.w},{b1r.x,b1r.y,b1r.z,b1r.w}};
            #pragma unroll
            for (int ri = 0; ri < 2; ++ri)
                #pragma unroll
                for (int i = 0; i < 4; ++i)
                    #pragma unroll
                    for (int rj = 0; rj < 2; ++rj)
                        #pragma unroll
                        for (int j = 0; j < 4; ++j)
                            acc[ri][rj][i][j] = fmaf(ar[ri][i], br[rj][j], acc[ri][rj][i][j]);
        }
        Aptr += FBK;
        Bptr += FBK * H_;
    }

    float ps[2][4][C_];
    #pragma unroll
    for (int ri = 0; ri < 2; ++ri)
        #pragma unroll
        for (int i = 0; i < 4; ++i)
            #pragma unroll
            for (int cc = 0; cc < C_; ++cc) ps[ri][i][cc] = 0.f;

    #pragma unroll
    for (int rj = 0; rj < 2; ++rj)
        #pragma unroll
        for (int j = 0; j < 4; ++j) {
            const int nl = rj * 64 + (tx << 2) + j;
            const float bj = b1[n0 + nl];
            float w2c[C_];
            #pragma unroll
            for (int cc = 0; cc < C_; ++cc) w2c[cc] = w2s[nl][cc];
            #pragma unroll
            for (int ri = 0; ri < 2; ++ri)
                #pragma unroll
                for (int i = 0; i < 4; ++i) {
                    float h = acc[ri][rj][i][j] + bj;
                    h = h > 0.f ? h : 0.f;
                    #pragma unroll
                    for (int cc = 0; cc < C_; ++cc)
                        ps[ri][i][cc] = fmaf(h, w2c[cc], ps[ri][i][cc]);
                }
        }

    #pragma unroll
    for (int off = 1; off < 16; off <<= 1)
        #pragma unroll
        for (int ri = 0; ri < 2; ++ri)
            #pragma unroll
            for (int i = 0; i < 4; ++i)
                #pragma unroll
                for (int cc = 0; cc < C_; ++cc)
                    ps[ri][i][cc] += __shfl_xor(ps[ri][i][cc], off, 64);

    if (tx == 0)
        #pragma unroll
        for (int ri = 0; ri < 2; ++ri)
            #pragma unroll
            for (int i = 0; i < 4; ++i) {
                const int m = m0 + ri * 64 + (ty << 2) + i;
                #pragma unroll
                for (int cc = 0; cc < C_; ++cc)
                    atomicAdd(&pot[m * C_ + cc], ps[ri][i][cc]);
            }
}

// =========================================================================
// Kernel 3: Viterbi via max-plus associative scan (verified).
// =========================================================================
__global__ __launch_bounds__(64) void viterbi_kernel(
    const float* __restrict__ pot, const float* __restrict__ trans,
    const int* __restrict__ mask, float* __restrict__ decoded,
    float* __restrict__ seqlen, float* __restrict__ chain_out)
{
    const int b = blockIdx.x;
    const int lane = threadIdx.x;

    __shared__ float pl[S_ * C_];
    __shared__ unsigned int bpk[S_];
    __shared__ unsigned int gseg[64];
    __shared__ int bt[64];
    __shared__ int dec_s[S_];
    __shared__ int s_last;

    const float* pb = pot + b * (S_ * C_);
    for (int i = lane; i < S_ * C_; i += 64) pl[i] = pb[i];

    int mcnt = 0;
    const int* mb = mask + b * S_;
    for (int i = lane; i < S_; i += 64) mcnt += (mb[i] != 0) ? 1 : 0;
    #pragma unroll
    for (int off = 32; off >= 1; off >>= 1) mcnt += __shfl_xor(mcnt, off, 64);

    if (b == 0 && lane < C_ * C_) chain_out[lane] = trans[lane];

    float tr[C_][C_];
    #pragma unroll
    for (int p = 0; p < C_; ++p)
        #pragma unroll
        for (int c = 0; c < C_; ++c) tr[p][c] = trans[p * C_ + c];

    __syncthreads();

    const float NEG = -1.0e30f;

    float G[C_][C_];
    #pragma unroll
    for (int c = 0; c < C_; ++c)
        #pragma unroll
        for (int p = 0; p < C_; ++p) G[c][p] = (c == p) ? 0.f : NEG;

    for (int j = 1; j <= 8; ++j) {
        const int t = 8 * lane + j;
        if (t < S_) {
            float ng[C_][C_];
            #pragma unroll
            for (int c = 0; c < C_; ++c) {
                const float pc = pl[t * C_ + c];
                #pragma unroll
                for (int p = 0; p < C_; ++p) {
                    float m = tr[0][c] + G[0][p];
                    #pragma unroll
                    for (int q = 1; q < C_; ++q)
                        m = fmaxf(m, tr[q][c] + G[q][p]);
                    ng[c][p] = m + pc;
                }
            }
            #pragma unroll
            for (int c = 0; c < C_; ++c)
                #pragma unroll
                for (int p = 0; p < C_; ++p) G[c][p] = ng[c][p];
        }
    }

    #pragma unroll
    for (int d = 1; d < 64; d <<= 1) {
        float Q[C_][C_];
        #pragma unroll
        for (int q = 0; q < C_; ++q)
            #pragma unroll
            for (int p = 0; p < C_; ++p) Q[q][p] = __shfl_up(G[q][p], d, 64);
        if (lane >= d) {
            float ng[C_][C_];
            #pragma unroll
            for (int c = 0; c < C_; ++c)
                #pragma unroll
                for (int p = 0; p < C_; ++p) {
                    float m = G[c][0] + Q[0][p];
                    #pragma unroll
                    for (int q = 1; q < C_; ++q)
                        m = fmaxf(m, G[c][q] + Q[q][p]);
                    ng[c][p] = m;
                }
            #pragma unroll
            for (int c = 0; c < C_; ++c)
                #pragma unroll
                for (int p = 0; p < C_; ++p) G[c][p] = ng[c][p];
        }
    }

    float a[C_];
    {
        float E[C_][C_];
        #pragma unroll
        for (int c = 0; c < C_; ++c)
            #pragma unroll
            for (int p = 0; p < C_; ++p) E[c][p] = __shfl_up(G[c][p], 1, 64);
        float a0[C_];
        #pragma unroll
        for (int c = 0; c < C_; ++c) a0[c] = pl[c];
        if (lane == 0) {
            #pragma unroll
            for (int c = 0; c < C_; ++c) a[c] = a0[c];
        } else {
            #pragma unroll
            for (int c = 0; c < C_; ++c) {
                float m = E[c][0] + a0[0];
                #pragma unroll
                for (int q = 1; q < C_; ++q) m = fmaxf(m, E[c][q] + a0[q]);
                a[c] = m;
            }
        }
    }

    for (int j = 1; j <= 8; ++j) {
        const int t = 8 * lane + j;
        if (t < S_) {
            unsigned int mpack = 0;
            float na[C_];
            #pragma unroll
            for (int c = 0; c < C_; ++c) {
                float best = a[0] + tr[0][c];
                int arg = 0;
                #pragma unroll
                for (int p = 1; p < C_; ++p) {
                    const float s = a[p] + tr[p][c];
                    if (s > best) { best = s; arg = p; }
                }
                mpack |= (unsigned int)arg << (3 * c);
                na[c] = best + pl[t * C_ + c];
            }
            bpk[t] = mpack;
            #pragma unroll
            for (int c = 0; c < C_; ++c) a[c] = na[c];
        }
    }

    if (lane == 63) {
        float best = a[0];
        int arg = 0;
        #pragma unroll
        for (int p = 1; p < C_; ++p)
            if (a[p] > best) { best = a[p]; arg = p; }
        s_last = arg;
    }
    if (lane == 0) bpk[0] = 0;
    __syncthreads();

    const int last = s_last;

    unsigned int g = 0u | (1u << 3) | (2u << 6) | (3u << 9) | (4u << 12);
    #pragma unroll
    for (int j = 7; j >= 0; --j) {
        const int t = 8 * lane + j;
        if (t >= 1) {
            const unsigned int m = bpk[t];
            unsigned int ng = 0;
            #pragma unroll
            for (int x = 0; x < C_; ++x) {
                const unsigned int gx = (g >> (3 * x)) & 7u;
                ng |= ((m >> (3 * gx)) & 7u) << (3 * x);
            }
            g = ng;
        }
    }
    gseg[lane] = g;
    __syncthreads();

    if (lane == 0) {
        int cur = last;
        for (int l = 63; l >= 0; --l) {
            bt[l] = cur;
            cur = (int)((gseg[l] >> (3 * cur)) & 7u);
        }
        seqlen[b] = (float)mcnt;
    }
    __syncthreads();

    {
        int tag = bt[lane];
        const int t0 = 8 * lane;
        dec_s[t0 + 7] = tag;
        #pragma unroll
        for (int t = t0 + 7; t >= t0 + 1; --t) {
            tag = (int)((bpk[t] >> (3 * tag)) & 7u);
            dec_s[t - 1] = tag;
        }
    }
    __syncthreads();

    float* db = decoded + b * S_;
    for (int i = lane; i < S_; i += 64) db[i] = (float)dec_s[i];
}

// =========================================================================
extern "C" void kernel_launch(void* const* d_in, const int* in_sizes, int n_in,
                              void* d_out, int out_size, void* d_ws, size_t ws_size,
                              hipStream_t stream) {
    const float* hs    = (const float*)d_in[0];
    const int*   mask  = (const int*)  d_in[1];
    const float* W1    = (const float*)d_in[2];
    const float* b1    = (const float*)d_in[3];
    const float* W2    = (const float*)d_in[4];
    const float* b2    = (const float*)d_in[5];
    const float* chain = (const float*)d_in[6];
    const float* lb    = (const float*)d_in[7];
    const float* rb    = (const float*)d_in[8];

    float* out      = (float*)d_out;
    float* decoded  = out;
    float* pot      = out + M_;
    float* seq      = out + M_ + M_ * C_;
    float* chainout = seq + B_;

    const size_t need_bf  = (size_t)W1T_ELEMS * 2 + (size_t)XBF_ELEMS * 2;   // 51.5 MB
    const size_t need_full = need_bf + (size_t)PART_ELEMS * 4;               // 56.8 MB

    if (ws_size >= need_full) {
        unsigned short* w1t = (unsigned short*)d_ws;
        unsigned short* xbf = w1t + W1T_ELEMS;
        float*          part = (float*)(xbf + XBF_ELEMS);
        prep_all_kernel<<<PX_BLOCKS + PW_BLOCKS, 256, 0, stream>>>(
            hs, W1, xbf, w1t);
        gemm_nres_t<false><<<256, 512, 0, stream>>>(xbf, w1t, b1, W2, part);
        reduce_pot_kernel<<<(M_ * C_ + 255) / 256, 256, 0, stream>>>(
            part, b2, lb, rb, pot);
    } else if (ws_size >= need_bf) {
        unsigned short* w1t = (unsigned short*)d_ws;
        unsigned short* xbf = w1t + W1T_ELEMS;
        init_pot_kernel<<<(M_ * C_ + 255) / 256, 256, 0, stream>>>(b2, lb, rb, pot);
        prep_all_kernel<<<PX_BLOCKS + PW_BLOCKS, 256, 0, stream>>>(
            hs, W1, xbf, w1t);
        gemm_nres_t<true><<<256, 512, 0, stream>>>(xbf, w1t, b1, W2, pot);
    } else {
        init_pot_kernel<<<(M_ * C_ + 255) / 256, 256, 0, stream>>>(b2, lb, rb, pot);
        dim3 grid(H_ / 128, M_ / 128);
        gemm_relu_pot_kernel<<<grid, 256, 0, stream>>>(hs, W1, b1, W2, pot);
    }

    viterbi_kernel<<<B_, 64, 0, stream>>>(pot, chain, mask, decoded, seq, chainout);
}

// Round 9
// 286.474 us; speedup vs baseline: 1.8036x; 1.7087x over previous
//
#include <hip/hip_runtime.h>

// Problem constants
#define B_  64
#define S_  512
#define D_  768
#define H_  768
#define C_  5
#define M_  (B_ * S_)        // 32768 rows

typedef float f32x4 __attribute__((ext_vector_type(4)));
typedef short short8 __attribute__((ext_vector_type(8)));   // bf16x8 MFMA operand

#define W1T_ELEMS (D_ * H_)      // 589824  (bf16: 1.18 MB)
#define XBF_ELEMS (M_ * D_)      // 25165824 (bf16: 50.33 MB)

// prep_all grid partition
#define PX_BLOCKS   (XBF_ELEMS / (256 * 8))          // 12288
#define PW_BLOCKS   ((D_ / 32) * (H_ / 32))          // 576

__device__ __forceinline__ unsigned short f2bf(float f) {
    unsigned int u = __float_as_uint(f);
    u += 0x7FFFu + ((u >> 16) & 1u);     // RNE
    return (unsigned short)(u >> 16);
}

__device__ __forceinline__ void gload16(const void* g, void* l) {
    __builtin_amdgcn_global_load_lds(
        (const __attribute__((address_space(1))) unsigned int*)g,
        (__attribute__((address_space(3))) unsigned int*)l, 16, 0, 0);
}

// =========================================================================
// Kernel 1: fused prep — prep_x | prep_w1
// =========================================================================
__global__ __launch_bounds__(256) void prep_all_kernel(
    const float* __restrict__ X, const float* __restrict__ W1,
    unsigned short* __restrict__ xbf, unsigned short* __restrict__ w1t)
{
    __shared__ float t[32][33];
    const int bid = blockIdx.x;
    const int tid = threadIdx.x;

    if (bid < PX_BLOCKS) {
        // ---- X fp32 -> bf16 ----
        const size_t i0 = ((size_t)bid * 256 + tid) * 8;
        const float4 a = *(const float4*)(X + i0);
        const float4 b = *(const float4*)(X + i0 + 4);
        union { unsigned short u[8]; uint4 v; } o;
        o.u[0] = f2bf(a.x); o.u[1] = f2bf(a.y); o.u[2] = f2bf(a.z); o.u[3] = f2bf(a.w);
        o.u[4] = f2bf(b.x); o.u[5] = f2bf(b.y); o.u[6] = f2bf(b.z); o.u[7] = f2bf(b.w);
        *(uint4*)(xbf + i0) = o.v;
    } else {
        // ---- W1 [k][n] fp32 -> w1t [n][k] bf16 (LDS-tiled transpose) ----
        const int b2i = bid - PX_BLOCKS;
        const int bx = b2i % (H_ / 32);       // n tile
        const int by = b2i / (H_ / 32);       // k tile
        const int lx = tid & 31, ly = tid >> 5;
        #pragma unroll
        for (int j = 0; j < 4; ++j)
            t[ly + 8 * j][lx] = W1[(by * 32 + ly + 8 * j) * H_ + bx * 32 + lx];
        __syncthreads();
        #pragma unroll
        for (int j = 0; j < 4; ++j)
            w1t[(size_t)(bx * 32 + ly + 8 * j) * D_ + by * 32 + lx] = f2bf(t[lx][ly + 8 * j]);
    }
}

__global__ __launch_bounds__(256) void init_pot_kernel(
    const float* __restrict__ b2, const float* __restrict__ lb,
    const float* __restrict__ rb, float* __restrict__ pot)
{
    const int idx = blockIdx.x * 256 + threadIdx.x;
    if (idx < M_ * C_) {
        const int c = idx % C_;
        const int t = (idx / C_) & (S_ - 1);
        float v = b2[c];
        if (t == 0)      v += lb[c];
        if (t == S_ - 1) v += rb[c];
        pot[idx] = v;
    }
}

// =========================================================================
// Kernel 2 (R9 = R8 with compile fix): A-RESIDENT in LDS, B streamed from L2.
//
// R5/R7 post-mortem: inter-block L2 convoying for A-reuse fails (FETCH
// 497/540 MB) and atomics add 248 MB of RMW write traffic. Invert
// residency: the only guaranteed-L2-resident operand is w1t (1.18 MB,
// hot in every XCD). Block = 64 rows x full N=768:
//   - A (64 x 768 bf16 = 96 KB) staged to LDS ONCE -> A read from HBM
//     exactly once chip-wide (50 MB), no inter-block timing assumptions.
//   - each wave owns 96 cols; B panel (147 KB/wave) streamed L2->regs per
//     kf step (24 unrolled independent steps: 6 global B + 4 LDS A + 24
//     MFMA) -- ILP + 2 waves/SIMD hide L2 latency (R5/R7 proved this
//     regime sustains 2.5 TB/s).
//   - full-N block -> complete pot rows: 8-wave LDS reduction (aliases
//     Alds) + direct store with b2/lb/rb folded. NO atomics, NO partials.
// Grid 512 x 64 rows = M exactly; 2 barriers total; LDS 96 KB (1 blk/CU).
// =========================================================================
__global__ __launch_bounds__(512, 1) void gemm_ares_kernel(
    const unsigned short* __restrict__ xbf,   // [M_, D_] bf16
    const unsigned short* __restrict__ w1t,   // [H_, D_] bf16 (n-major)
    const float* __restrict__ b1,
    const float* __restrict__ W2,             // [H_, C_]
    const float* __restrict__ b2,
    const float* __restrict__ lb,
    const float* __restrict__ rb,
    float* __restrict__ pot)                  // [M_, C_] written directly
{
    // A slab: [4 row-groups][24 kf][512 shorts]; 512 = 16 rows x 32 k
    __shared__ __align__(16) unsigned short Alds[4 * 24 * 512];   // 96 KB

    const int tid  = threadIdx.x;
    const int lane = tid & 63, w = tid >> 6;       // wave 0..7
    const int i15  = lane & 15, quad = lane >> 4;
    const int rowb = blockIdx.x * 64;

    // ---- one-time A staging: 96 subtiles (1 KB each); wave w does 12 ----
    #pragma unroll
    for (int j = 0; j < 12; ++j) {
        const int idx = w * 12 + j;            // 0..95
        const int g = idx / 24, kf = idx % 24; // row-group, k-fragment
        const unsigned short* src =
            xbf + (size_t)(rowb + g * 16 + i15) * D_ + kf * 32 + quad * 8;
        gload16(src, &Alds[idx * 512]);
    }
    __syncthreads();   // drains vmcnt(0): A slab visible to all waves

    // ---- B panel base pointers: wave w owns cols [96w, 96w+96) ----
    const unsigned short* bw[6];
    #pragma unroll
    for (int ni = 0; ni < 6; ++ni)
        bw[ni] = w1t + (size_t)(w * 96 + ni * 16 + i15) * D_ + quad * 8;

    f32x4 acc[4][6];
    #pragma unroll
    for (int mi = 0; mi < 4; ++mi)
        #pragma unroll
        for (int ni = 0; ni < 6; ++ni)
            acc[mi][ni] = (f32x4){0.f, 0.f, 0.f, 0.f};

    // ---- barrier-free compute: 24 independent kf steps ----
    #pragma unroll
    for (int kf = 0; kf < 24; ++kf) {
        short8 bfr[6], af[4];
        #pragma unroll
        for (int ni = 0; ni < 6; ++ni)
            bfr[ni] = *(const short8*)(bw[ni] + kf * 32);
        #pragma unroll
        for (int mi = 0; mi < 4; ++mi)
            af[mi] = *(const short8*)&Alds[(mi * 24 + kf) * 512 + lane * 8];
        #pragma unroll
        for (int ni = 0; ni < 6; ++ni)
            #pragma unroll
            for (int mi = 0; mi < 4; ++mi)
                acc[mi][ni] = __builtin_amdgcn_mfma_f32_16x16x32_bf16(
                    af[mi], bfr[ni], acc[mi][ni], 0, 0, 0);
    }

    // ---- epilogue: relu(h+b1)@W2, per-wave col-slice partials ----
    float b1v[6], w2v[6][C_];
    #pragma unroll
    for (int ni = 0; ni < 6; ++ni) {
        const int col = w * 96 + ni * 16 + i15;
        b1v[ni] = b1[col];
        #pragma unroll
        for (int cc = 0; cc < C_; ++cc) w2v[ni][cc] = W2[col * C_ + cc];
    }

    __syncthreads();   // all Alds reads done before pp aliases it
    float* pp = (float*)&Alds[0];            // [8][64][C_] = 10240 B

    #pragma unroll
    for (int mi = 0; mi < 4; ++mi) {
        float ps[4][C_];
        #pragma unroll
        for (int r = 0; r < 4; ++r)
            #pragma unroll
            for (int cc = 0; cc < C_; ++cc) ps[r][cc] = 0.f;

        #pragma unroll
        for (int ni = 0; ni < 6; ++ni)
            #pragma unroll
            for (int r = 0; r < 4; ++r) {
                float hh = acc[mi][ni][r] + b1v[ni];
                hh = hh > 0.f ? hh : 0.f;
                #pragma unroll
                for (int cc = 0; cc < C_; ++cc)
                    ps[r][cc] = fmaf(hh, w2v[ni][cc], ps[r][cc]);
            }

        // reduce over the 16 cols held across i15 lanes (quad = rows)
        #pragma unroll
        for (int off = 1; off < 16; off <<= 1)
            #pragma unroll
            for (int r = 0; r < 4; ++r)
                #pragma unroll
                for (int cc = 0; cc < C_; ++cc)
                    ps[r][cc] += __shfl_xor(ps[r][cc], off, 64);

        if (i15 == 0) {
            #pragma unroll
            for (int r = 0; r < 4; ++r) {
                const int row = mi * 16 + quad * 4 + r;   // 0..63
                #pragma unroll
                for (int cc = 0; cc < C_; ++cc)
                    pp[(w * 64 + row) * C_ + cc] = ps[r][cc];
            }
        }
    }
    __syncthreads();

    // ---- final: sum 8 wave-slices + b2/boundaries -> direct pot store ----
    for (int idx = tid; idx < 64 * C_; idx += 512) {
        const int row = idx / C_, cc = idx % C_;
        float s = b2[cc];
        #pragma unroll
        for (int wv = 0; wv < 8; ++wv)
            s += pp[(wv * 64 + row) * C_ + cc];
        const int gm = rowb + row;
        const int tt = gm & (S_ - 1);
        if (tt == 0)      s += lb[cc];
        if (tt == S_ - 1) s += rb[cc];
        pot[(size_t)gm * C_ + cc] = s;
    }
}

// =========================================================================
// Last-resort fp32 GEMM if ws too small for xbf+w1t
// =========================================================================
#define FBK 8
#define FLDS 132
__global__ __launch_bounds__(256) void gemm_relu_pot_kernel(
    const float* __restrict__ X, const float* __restrict__ W1,
    const float* __restrict__ b1, const float* __restrict__ W2,
    float* __restrict__ pot)
{
    __shared__ float As[FBK * FLDS];
    __shared__ float Bs[FBK * FLDS];
    __shared__ float w2s[128][C_];

    const int tid = threadIdx.x;
    const int tx = tid & 15, ty = tid >> 4;
    const int m0 = blockIdx.y * 128, n0 = blockIdx.x * 128;

    for (int idx = tid; idx < 128 * C_; idx += 256)
        w2s[idx / C_][idx % C_] = W2[(n0 + idx / C_) * C_ + idx % C_];

    float acc[2][2][4][4];
    #pragma unroll
    for (int a = 0; a < 2; ++a)
        #pragma unroll
        for (int b = 0; b < 2; ++b)
            #pragma unroll
            for (int i = 0; i < 4; ++i)
                #pragma unroll
                for (int j = 0; j < 4; ++j) acc[a][b][i][j] = 0.f;

    const int arow = tid >> 1, aq = tid & 1;
    const int brow = tid >> 5, bq = tid & 31;
    const float* Aptr = X + (m0 + arow) * D_ + aq * 4;
    const float* Bptr = W1 + brow * H_ + n0 + bq * 4;

    for (int kt = 0; kt < D_; kt += FBK) {
        const float4 avv = *(const float4*)Aptr;
        const float4 bvv = *(const float4*)Bptr;
        __syncthreads();
        As[(aq * 4 + 0) * FLDS + arow] = avv.x;
        As[(aq * 4 + 1) * FLDS + arow] = avv.y;
        As[(aq * 4 + 2) * FLDS + arow] = avv.z;
        As[(aq * 4 + 3) * FLDS + arow] = avv.w;
        *(float4*)&Bs[brow * FLDS + bq * 4] = bvv;
        __syncthreads();
        #pragma unroll
        for (int k = 0; k < FBK; ++k) {
            const float4 a0 = *(const float4*)&As[k * FLDS + (ty << 2)];
            const float4 a1 = *(const float4*)&As[k * FLDS + 64 + (ty << 2)];
            const float4 b0 = *(const float4*)&Bs[k * FLDS + (tx << 2)];
            const float4 b1r = *(const float4*)&Bs[k * FLDS + 64 + (tx << 2)];
            const float ar[2][4] = {{a0.x,a0.y,a0.z,a0.w},{a1.x,a1.y,a1.z,a1.w}};
            const float br[2][4] = {{b0.x,b0.y,b0.z,b0.w},{b1r.x,b1r.y,b1r.z,b1r.w}};
            #pragma unroll
            for (int ri = 0; ri < 2; ++ri)
                #pragma unroll
                for (int i = 0; i < 4; ++i)
                    #pragma unroll
                    for (int rj = 0; rj < 2; ++rj)
                        #pragma unroll
                        for (int j = 0; j < 4; ++j)
                            acc[ri][rj][i][j] = fmaf(ar[ri][i], br[rj][j], acc[ri][rj][i][j]);
        }
        Aptr += FBK;
        Bptr += FBK * H_;
    }

    float ps[2][4][C_];
    #pragma unroll
    for (int ri = 0; ri < 2; ++ri)
        #pragma unroll
        for (int i = 0; i < 4; ++i)
            #pragma unroll
            for (int cc = 0; cc < C_; ++cc) ps[ri][i][cc] = 0.f;

    #pragma unroll
    for (int rj = 0; rj < 2; ++rj)
        #pragma unroll
        for (int j = 0; j < 4; ++j) {
            const int nl = rj * 64 + (tx << 2) + j;
            const float bj = b1[n0 + nl];
            float w2c[C_];
            #pragma unroll
            for (int cc = 0; cc < C_; ++cc) w2c[cc] = w2s[nl][cc];
            #pragma unroll
            for (int ri = 0; ri < 2; ++ri)
                #pragma unroll
                for (int i = 0; i < 4; ++i) {
                    float h = acc[ri][rj][i][j] + bj;
                    h = h > 0.f ? h : 0.f;
                    #pragma unroll
                    for (int cc = 0; cc < C_; ++cc)
                        ps[ri][i][cc] = fmaf(h, w2c[cc], ps[ri][i][cc]);
                }
        }

    #pragma unroll
    for (int off = 1; off < 16; off <<= 1)
        #pragma unroll
        for (int ri = 0; ri < 2; ++ri)
            #pragma unroll
            for (int i = 0; i < 4; ++i)
                #pragma unroll
                for (int cc = 0; cc < C_; ++cc)
                    ps[ri][i][cc] += __shfl_xor(ps[ri][i][cc], off, 64);

    if (tx == 0)
        #pragma unroll
        for (int ri = 0; ri < 2; ++ri)
            #pragma unroll
            for (int i = 0; i < 4; ++i) {
                const int m = m0 + ri * 64 + (ty << 2) + i;
                #pragma unroll
                for (int cc = 0; cc < C_; ++cc)
                    atomicAdd(&pot[m * C_ + cc], ps[ri][i][cc]);
            }
}

// =========================================================================
// Kernel 3: Viterbi via max-plus associative scan (verified).
// =========================================================================
__global__ __launch_bounds__(64) void viterbi_kernel(
    const float* __restrict__ pot, const float* __restrict__ trans,
    const int* __restrict__ mask, float* __restrict__ decoded,
    float* __restrict__ seqlen, float* __restrict__ chain_out)
{
    const int b = blockIdx.x;
    const int lane = threadIdx.x;

    __shared__ float pl[S_ * C_];
    __shared__ unsigned int bpk[S_];
    __shared__ unsigned int gseg[64];
    __shared__ int bt[64];
    __shared__ int dec_s[S_];
    __shared__ int s_last;

    const float* pb = pot + b * (S_ * C_);
    for (int i = lane; i < S_ * C_; i += 64) pl[i] = pb[i];

    int mcnt = 0;
    const int* mb = mask + b * S_;
    for (int i = lane; i < S_; i += 64) mcnt += (mb[i] != 0) ? 1 : 0;
    #pragma unroll
    for (int off = 32; off >= 1; off >>= 1) mcnt += __shfl_xor(mcnt, off, 64);

    if (b == 0 && lane < C_ * C_) chain_out[lane] = trans[lane];

    float tr[C_][C_];
    #pragma unroll
    for (int p = 0; p < C_; ++p)
        #pragma unroll
        for (int c = 0; c < C_; ++c) tr[p][c] = trans[p * C_ + c];

    __syncthreads();

    const float NEG = -1.0e30f;

    float G[C_][C_];
    #pragma unroll
    for (int c = 0; c < C_; ++c)
        #pragma unroll
        for (int p = 0; p < C_; ++p) G[c][p] = (c == p) ? 0.f : NEG;

    for (int j = 1; j <= 8; ++j) {
        const int t = 8 * lane + j;
        if (t < S_) {
            float ng[C_][C_];
            #pragma unroll
            for (int c = 0; c < C_; ++c) {
                const float pc = pl[t * C_ + c];
                #pragma unroll
                for (int p = 0; p < C_; ++p) {
                    float m = tr[0][c] + G[0][p];
                    #pragma unroll
                    for (int q = 1; q < C_; ++q)
                        m = fmaxf(m, tr[q][c] + G[q][p]);
                    ng[c][p] = m + pc;
                }
            }
            #pragma unroll
            for (int c = 0; c < C_; ++c)
                #pragma unroll
                for (int p = 0; p < C_; ++p) G[c][p] = ng[c][p];
        }
    }

    #pragma unroll
    for (int d = 1; d < 64; d <<= 1) {
        float Q[C_][C_];
        #pragma unroll
        for (int q = 0; q < C_; ++q)
            #pragma unroll
            for (int p = 0; p < C_; ++p) Q[q][p] = __shfl_up(G[q][p], d, 64);
        if (lane >= d) {
            float ng[C_][C_];
            #pragma unroll
            for (int c = 0; c < C_; ++c)
                #pragma unroll
                for (int p = 0; p < C_; ++p) {
                    float m = G[c][0] + Q[0][p];
                    #pragma unroll
                    for (int q = 1; q < C_; ++q)
                        m = fmaxf(m, G[c][q] + Q[q][p]);
                    ng[c][p] = m;
                }
            #pragma unroll
            for (int c = 0; c < C_; ++c)
                #pragma unroll
                for (int p = 0; p < C_; ++p) G[c][p] = ng[c][p];
        }
    }

    float a[C_];
    {
        float E[C_][C_];
        #pragma unroll
        for (int c = 0; c < C_; ++c)
            #pragma unroll
            for (int p = 0; p < C_; ++p) E[c][p] = __shfl_up(G[c][p], 1, 64);
        float a0[C_];
        #pragma unroll
        for (int c = 0; c < C_; ++c) a0[c] = pl[c];
        if (lane == 0) {
            #pragma unroll
            for (int c = 0; c < C_; ++c) a[c] = a0[c];
        } else {
            #pragma unroll
            for (int c = 0; c < C_; ++c) {
                float m = E[c][0] + a0[0];
                #pragma unroll
                for (int q = 1; q < C_; ++q) m = fmaxf(m, E[c][q] + a0[q]);
                a[c] = m;
            }
        }
    }

    for (int j = 1; j <= 8; ++j) {
        const int t = 8 * lane + j;
        if (t < S_) {
            unsigned int mpack = 0;
            float na[C_];
            #pragma unroll
            for (int c = 0; c < C_; ++c) {
                float best = a[0] + tr[0][c];
                int arg = 0;
                #pragma unroll
                for (int p = 1; p < C_; ++p) {
                    const float s = a[p] + tr[p][c];
                    if (s > best) { best = s; arg = p; }
                }
                mpack |= (unsigned int)arg << (3 * c);
                na[c] = best + pl[t * C_ + c];
            }
            bpk[t] = mpack;
            #pragma unroll
            for (int c = 0; c < C_; ++c) a[c] = na[c];
        }
    }

    if (lane == 63) {
        float best = a[0];
        int arg = 0;
        #pragma unroll
        for (int p = 1; p < C_; ++p)
            if (a[p] > best) { best = a[p]; arg = p; }
        s_last = arg;
    }
    if (lane == 0) bpk[0] = 0;
    __syncthreads();

    const int last = s_last;

    unsigned int g = 0u | (1u << 3) | (2u << 6) | (3u << 9) | (4u << 12);
    #pragma unroll
    for (int j = 7; j >= 0; --j) {
        const int t = 8 * lane + j;
        if (t >= 1) {
            const unsigned int m = bpk[t];
            unsigned int ng = 0;
            #pragma unroll
            for (int x = 0; x < C_; ++x) {
                const unsigned int gx = (g >> (3 * x)) & 7u;
                ng |= ((m >> (3 * gx)) & 7u) << (3 * x);
            }
            g = ng;
        }
    }
    gseg[lane] = g;
    __syncthreads();

    if (lane == 0) {
        int cur = last;
        for (int l = 63; l >= 0; --l) {
            bt[l] = cur;
            cur = (int)((gseg[l] >> (3 * cur)) & 7u);
        }
        seqlen[b] = (float)mcnt;
    }
    __syncthreads();

    {
        int tag = bt[lane];
        const int t0 = 8 * lane;
        dec_s[t0 + 7] = tag;
        #pragma unroll
        for (int t = t0 + 7; t >= t0 + 1; --t) {
            tag = (int)((bpk[t] >> (3 * tag)) & 7u);
            dec_s[t - 1] = tag;
        }
    }
    __syncthreads();

    float* db = decoded + b * S_;
    for (int i = lane; i < S_; i += 64) db[i] = (float)dec_s[i];
}

// =========================================================================
extern "C" void kernel_launch(void* const* d_in, const int* in_sizes, int n_in,
                              void* d_out, int out_size, void* d_ws, size_t ws_size,
                              hipStream_t stream) {
    const float* hs    = (const float*)d_in[0];
    const int*   mask  = (const int*)  d_in[1];
    const float* W1    = (const float*)d_in[2];
    const float* b1    = (const float*)d_in[3];
    const float* W2    = (const float*)d_in[4];
    const float* b2    = (const float*)d_in[5];
    const float* chain = (const float*)d_in[6];
    const float* lb    = (const float*)d_in[7];
    const float* rb    = (const float*)d_in[8];

    float* out      = (float*)d_out;
    float* decoded  = out;
    float* pot      = out + M_;
    float* seq      = out + M_ + M_ * C_;
    float* chainout = seq + B_;

    const size_t need_bf = (size_t)W1T_ELEMS * 2 + (size_t)XBF_ELEMS * 2;   // 51.5 MB

    if (ws_size >= need_bf) {
        unsigned short* w1t = (unsigned short*)d_ws;
        unsigned short* xbf = w1t + W1T_ELEMS;
        prep_all_kernel<<<PX_BLOCKS + PW_BLOCKS, 256, 0, stream>>>(
            hs, W1, xbf, w1t);
        gemm_ares_kernel<<<M_ / 64, 512, 0, stream>>>(
            xbf, w1t, b1, W2, b2, lb, rb, pot);
    } else {
        init_pot_kernel<<<(M_ * C_ + 255) / 256, 256, 0, stream>>>(b2, lb, rb, pot);
        dim3 grid(H_ / 128, M_ / 128);
        gemm_relu_pot_kernel<<<grid, 256, 0, stream>>>(hs, W1, b1, W2, pot);
    }

    viterbi_kernel<<<B_, 64, 0, stream>>>(pot, chain, mask, decoded, seq, chainout);
}

// Round 10
// 255.586 us; speedup vs baseline: 2.0215x; 1.1208x over previous
//
#include <hip/hip_runtime.h>

// Problem constants
#define B_  64
#define S_  512
#define D_  768
#define H_  768
#define C_  5
#define M_  (B_ * S_)        // 32768 rows

typedef float f32x4 __attribute__((ext_vector_type(4)));
typedef short short8 __attribute__((ext_vector_type(8)));   // bf16x8 MFMA operand

#define W1T_ELEMS (D_ * H_)          // 589824  (bf16: 1.18 MB)
#define PART2_ELEMS (2 * M_ * C_)    // 327680 floats = 1.31 MB

__device__ __forceinline__ unsigned short f2bf(float f) {
    unsigned int u = __float_as_uint(f);
    u += 0x7FFFu + ((u >> 16) & 1u);     // RNE
    return (unsigned short)(u >> 16);
}

// =========================================================================
// prep: W1 [k][n] fp32 -> w1t [n][k] bf16 (LDS-tiled transpose). ~3 us.
// =========================================================================
__global__ __launch_bounds__(256) void prep_w1_kernel(
    const float* __restrict__ W1, unsigned short* __restrict__ w1t)
{
    __shared__ float t[32][33];
    const int bx = blockIdx.x, by = blockIdx.y;
    const int lx = threadIdx.x & 31, ly = threadIdx.x >> 5;
    #pragma unroll
    for (int j = 0; j < 4; ++j)
        t[ly + 8 * j][lx] = W1[(by * 32 + ly + 8 * j) * H_ + bx * 32 + lx];
    __syncthreads();
    #pragma unroll
    for (int j = 0; j < 4; ++j)
        w1t[(size_t)(bx * 32 + ly + 8 * j) * D_ + by * 32 + lx] = f2bf(t[lx][ly + 8 * j]);
}

__global__ __launch_bounds__(256) void init_pot_kernel(
    const float* __restrict__ b2, const float* __restrict__ lb,
    const float* __restrict__ rb, float* __restrict__ pot)
{
    const int idx = blockIdx.x * 256 + threadIdx.x;
    if (idx < M_ * C_) {
        const int c = idx % C_;
        const int t = (idx / C_) & (S_ - 1);
        float v = b2[c];
        if (t == 0)      v += lb[c];
        if (t == S_ - 1) v += rb[c];
        pot[idx] = v;
    }
}

// =========================================================================
// Kernel 2 (R10): 128 rows x half-N (384 cols) per block, fp32-X direct.
//
// R0-R9 unified model: time = VMEM-instruction bytes / ~6.2 TB/s
// (~10 B/cy/CU), regardless of barriers/schedule/cache level (R0 2.36MB/CU
// -> 95us; R9 654MB -> 107us, both exact). B re-read = 1.18MB x M/R, so
// double R to 128 and delete the prep-X pass (X read fp32 ONCE per n-half,
// converted in-register during LDS staging). Half-N keeps acc at the
// proven 96 VGPR (8m x 3n frags/wave). A K-tiled in LDS (2 x 16 KB dbuf,
// async-split staging: issue loads -> compute -> cvt+ds_write -> bar).
// B streamed L2->regs (w1t 1.18 MB stays L2-hot). Output: per-wave
// partials -> pp LDS -> plain stores to part[2][M][5] (ws need 2.5 MB);
// reduce_pot folds b2/boundaries. No atomics, no init_pot, no xbf.
// Bytes: X 200 + B 302 + ~8 = ~510 MB -> ~82 us predicted.
// =========================================================================
__global__ __launch_bounds__(512) void gemm_half_kernel(
    const float* __restrict__ X,              // [M_, D_] fp32
    const unsigned short* __restrict__ w1t,   // [H_, D_] bf16 (n-major)
    const float* __restrict__ b1,
    const float* __restrict__ W2,             // [H_, C_]
    float* __restrict__ part)                 // [2][M_][C_] partials
{
    // A tile: [2 buf][128 rows x 64 k] bf16; subtile layout (row,k):
    //   off = ((row>>4)*2 + (k>>5))*512 + (((k>>3)&3)*16 + (row&15))*8
    __shared__ __align__(16) unsigned short At[2][8192];   // 32 KB
    __shared__ float pp[8][128][C_];                       // 20 KB

    const int tid  = threadIdx.x;
    const int lane = tid & 63, w = tid >> 6;       // wave 0..7
    const int i15  = lane & 15, quad = lane >> 4;

    const int bid  = blockIdx.x;
    const int nh   = bid & 1;           // n-half 0..1
    const int rg   = bid >> 1;          // row-group 0..255
    const int rowb = rg * 128;
    const int ncol0 = nh * 384 + w * 48;   // wave's first col

    // B pointers: wave owns cols [ncol0, ncol0+48), 3 n-frags
    const unsigned short* bw[3];
    #pragma unroll
    for (int ni = 0; ni < 3; ++ni)
        bw[ni] = w1t + (size_t)(ncol0 + ni * 16 + i15) * D_ + quad * 8;

    // A staging map: thread handles (row = tid>>2, 16 k-floats at (tid&3)*16)
    const int arow = tid >> 2;              // 0..127
    const int ak4  = tid & 3;               // k-quarter of the 64-k tile
    const float* aSrc = X + (size_t)(rowb + arow) * D_ + ak4 * 16;
    const int o0 = ak4 * 2, o1 = ak4 * 2 + 1;   // two k-octets
    const int dst0 = ((arow >> 4) * 2 + (o0 >> 2)) * 512 + ((o0 & 3) * 16 + (arow & 15)) * 8;
    const int dst1 = ((arow >> 4) * 2 + (o1 >> 2)) * 512 + ((o1 & 3) * 16 + (arow & 15)) * 8;

    f32x4 acc[8][3];
    #pragma unroll
    for (int mi = 0; mi < 8; ++mi)
        #pragma unroll
        for (int ni = 0; ni < 3; ++ni)
            acc[mi][ni] = (f32x4){0.f, 0.f, 0.f, 0.f};

    // ---- prologue: stage tile 0 into buf 0 ----
    {
        const float4 xa = *(const float4*)(aSrc);
        const float4 xb = *(const float4*)(aSrc + 4);
        const float4 xc = *(const float4*)(aSrc + 8);
        const float4 xd = *(const float4*)(aSrc + 12);
        union { unsigned short u[8]; uint4 v; } p, q;
        p.u[0] = f2bf(xa.x); p.u[1] = f2bf(xa.y); p.u[2] = f2bf(xa.z); p.u[3] = f2bf(xa.w);
        p.u[4] = f2bf(xb.x); p.u[5] = f2bf(xb.y); p.u[6] = f2bf(xb.z); p.u[7] = f2bf(xb.w);
        q.u[0] = f2bf(xc.x); q.u[1] = f2bf(xc.y); q.u[2] = f2bf(xc.z); q.u[3] = f2bf(xc.w);
        q.u[4] = f2bf(xd.x); q.u[5] = f2bf(xd.y); q.u[6] = f2bf(xd.z); q.u[7] = f2bf(xd.w);
        *(uint4*)&At[0][dst0] = p.v;
        *(uint4*)&At[0][dst1] = q.v;
    }
    __syncthreads();

    // ---- main loop: 12 K-tiles of 64 ----
    for (int kt = 0; kt < 12; ++kt) {
        const int cur = kt & 1;
        const bool pre = (kt < 11);

        // async-split: issue next tile's global loads first
        float4 xa, xb, xc, xd;
        if (pre) {
            const float* s = aSrc + (kt + 1) * 64;
            xa = *(const float4*)(s);
            xb = *(const float4*)(s + 4);
            xc = *(const float4*)(s + 8);
            xd = *(const float4*)(s + 12);
        }

        // compute current tile (latency of the above hides under this)
        #pragma unroll
        for (int kh = 0; kh < 2; ++kh) {
            short8 af[8], bfr[3];
            #pragma unroll
            for (int mi = 0; mi < 8; ++mi)
                af[mi] = *(const short8*)&At[cur][(mi * 2 + kh) * 512 + lane * 8];
            #pragma unroll
            for (int ni = 0; ni < 3; ++ni)
                bfr[ni] = *(const short8*)(bw[ni] + kt * 64 + kh * 32);
            #pragma unroll
            for (int ni = 0; ni < 3; ++ni)
                #pragma unroll
                for (int mi = 0; mi < 8; ++mi)
                    acc[mi][ni] = __builtin_amdgcn_mfma_f32_16x16x32_bf16(
                        af[mi], bfr[ni], acc[mi][ni], 0, 0, 0);
        }

        // convert + write next tile into the other buffer
        if (pre) {
            union { unsigned short u[8]; uint4 v; } p, q;
            p.u[0] = f2bf(xa.x); p.u[1] = f2bf(xa.y); p.u[2] = f2bf(xa.z); p.u[3] = f2bf(xa.w);
            p.u[4] = f2bf(xb.x); p.u[5] = f2bf(xb.y); p.u[6] = f2bf(xb.z); p.u[7] = f2bf(xb.w);
            q.u[0] = f2bf(xc.x); q.u[1] = f2bf(xc.y); q.u[2] = f2bf(xc.z); q.u[3] = f2bf(xc.w);
            q.u[4] = f2bf(xd.x); q.u[5] = f2bf(xd.y); q.u[6] = f2bf(xd.z); q.u[7] = f2bf(xd.w);
            *(uint4*)&At[cur ^ 1][dst0] = p.v;
            *(uint4*)&At[cur ^ 1][dst1] = q.v;
        }
        __syncthreads();
    }

    // ---- epilogue: relu(h+b1)@W2, wave-partial -> pp -> part store ----
    float b1v[3], w2v[3][C_];
    #pragma unroll
    for (int ni = 0; ni < 3; ++ni) {
        const int col = ncol0 + ni * 16 + i15;
        b1v[ni] = b1[col];
        #pragma unroll
        for (int cc = 0; cc < C_; ++cc) w2v[ni][cc] = W2[col * C_ + cc];
    }

    #pragma unroll
    for (int mi = 0; mi < 8; ++mi) {
        float ps[4][C_];
        #pragma unroll
        for (int r = 0; r < 4; ++r)
            #pragma unroll
            for (int cc = 0; cc < C_; ++cc) ps[r][cc] = 0.f;

        #pragma unroll
        for (int ni = 0; ni < 3; ++ni)
            #pragma unroll
            for (int r = 0; r < 4; ++r) {
                float hh = acc[mi][ni][r] + b1v[ni];
                hh = hh > 0.f ? hh : 0.f;
                #pragma unroll
                for (int cc = 0; cc < C_; ++cc)
                    ps[r][cc] = fmaf(hh, w2v[ni][cc], ps[r][cc]);
            }

        // reduce over the 16 cols held across i15 lanes (quad = rows)
        #pragma unroll
        for (int off = 1; off < 16; off <<= 1)
            #pragma unroll
            for (int r = 0; r < 4; ++r)
                #pragma unroll
                for (int cc = 0; cc < C_; ++cc)
                    ps[r][cc] += __shfl_xor(ps[r][cc], off, 64);

        if (i15 == 0) {
            #pragma unroll
            for (int r = 0; r < 4; ++r) {
                const int row = mi * 16 + quad * 4 + r;   // 0..127
                #pragma unroll
                for (int cc = 0; cc < C_; ++cc)
                    pp[w][row][cc] = ps[r][cc];
            }
        }
    }
    __syncthreads();

    for (int idx = tid; idx < 128 * C_; idx += 512) {
        const int row = idx / C_, cc = idx % C_;
        float s = 0.f;
        #pragma unroll
        for (int wv = 0; wv < 8; ++wv)
            s += pp[wv][row][cc];
        part[((size_t)nh * M_ + rowb + row) * C_ + cc] = s;
    }
}

// =========================================================================
// Kernel 2b: reduce 2 partials + b2/boundaries -> pot
// =========================================================================
__global__ __launch_bounds__(256) void reduce_pot_kernel(
    const float* __restrict__ part, const float* __restrict__ b2,
    const float* __restrict__ lb, const float* __restrict__ rb,
    float* __restrict__ pot)
{
    const int idx = blockIdx.x * 256 + threadIdx.x;
    if (idx < M_ * C_) {
        const int c = idx % C_;
        const int t = (idx / C_) & (S_ - 1);
        float v = b2[c];
        if (t == 0)      v += lb[c];
        if (t == S_ - 1) v += rb[c];
        v += part[idx] + part[(size_t)(M_ * C_) + idx];
        pot[idx] = v;
    }
}

// =========================================================================
// Last-resort fp32 GEMM if ws too small
// =========================================================================
#define FBK 8
#define FLDS 132
__global__ __launch_bounds__(256) void gemm_relu_pot_kernel(
    const float* __restrict__ X, const float* __restrict__ W1,
    const float* __restrict__ b1, const float* __restrict__ W2,
    float* __restrict__ pot)
{
    __shared__ float As[FBK * FLDS];
    __shared__ float Bs[FBK * FLDS];
    __shared__ float w2s[128][C_];

    const int tid = threadIdx.x;
    const int tx = tid & 15, ty = tid >> 4;
    const int m0 = blockIdx.y * 128, n0 = blockIdx.x * 128;

    for (int idx = tid; idx < 128 * C_; idx += 256)
        w2s[idx / C_][idx % C_] = W2[(n0 + idx / C_) * C_ + idx % C_];

    float acc[2][2][4][4];
    #pragma unroll
    for (int a = 0; a < 2; ++a)
        #pragma unroll
        for (int b = 0; b < 2; ++b)
            #pragma unroll
            for (int i = 0; i < 4; ++i)
                #pragma unroll
                for (int j = 0; j < 4; ++j) acc[a][b][i][j] = 0.f;

    const int arow = tid >> 1, aq = tid & 1;
    const int brow = tid >> 5, bq = tid & 31;
    const float* Aptr = X + (m0 + arow) * D_ + aq * 4;
    const float* Bptr = W1 + brow * H_ + n0 + bq * 4;

    for (int kt = 0; kt < D_; kt += FBK) {
        const float4 avv = *(const float4*)Aptr;
        const float4 bvv = *(const float4*)Bptr;
        __syncthreads();
        As[(aq * 4 + 0) * FLDS + arow] = avv.x;
        As[(aq * 4 + 1) * FLDS + arow] = avv.y;
        As[(aq * 4 + 2) * FLDS + arow] = avv.z;
        As[(aq * 4 + 3) * FLDS + arow] = avv.w;
        *(float4*)&Bs[brow * FLDS + bq * 4] = bvv;
        __syncthreads();
        #pragma unroll
        for (int k = 0; k < FBK; ++k) {
            const float4 a0 = *(const float4*)&As[k * FLDS + (ty << 2)];
            const float4 a1 = *(const float4*)&As[k * FLDS + 64 + (ty << 2)];
            const float4 b0 = *(const float4*)&Bs[k * FLDS + (tx << 2)];
            const float4 b1r = *(const float4*)&Bs[k * FLDS + 64 + (tx << 2)];
            const float ar[2][4] = {{a0.x,a0.y,a0.z,a0.w},{a1.x,a1.y,a1.z,a1.w}};
            const float br[2][4] = {{b0.x,b0.y,b0.z,b0.w},{b1r.x,b1r.y,b1r.z,b1r.w}};
            #pragma unroll
            for (int ri = 0; ri < 2; ++ri)
                #pragma unroll
                for (int i = 0; i < 4; ++i)
                    #pragma unroll
                    for (int rj = 0; rj < 2; ++rj)
                        #pragma unroll
                        for (int j = 0; j < 4; ++j)
                            acc[ri][rj][i][j] = fmaf(ar[ri][i], br[rj][j], acc[ri][rj][i][j]);
        }
        Aptr += FBK;
        Bptr += FBK * H_;
    }

    float ps[2][4][C_];
    #pragma unroll
    for (int ri = 0; ri < 2; ++ri)
        #pragma unroll
        for (int i = 0; i < 4; ++i)
            #pragma unroll
            for (int cc = 0; cc < C_; ++cc) ps[ri][i][cc] = 0.f;

    #pragma unroll
    for (int rj = 0; rj < 2; ++rj)
        #pragma unroll
        for (int j = 0; j < 4; ++j) {
            const int nl = rj * 64 + (tx << 2) + j;
            const float bj = b1[n0 + nl];
            float w2c[C_];
            #pragma unroll
            for (int cc = 0; cc < C_; ++cc) w2c[cc] = w2s[nl][cc];
            #pragma unroll
            for (int ri = 0; ri < 2; ++ri)
                #pragma unroll
                for (int i = 0; i < 4; ++i) {
                    float h = acc[ri][rj][i][j] + bj;
                    h = h > 0.f ? h : 0.f;
                    #pragma unroll
                    for (int cc = 0; cc < C_; ++cc)
                        ps[ri][i][cc] = fmaf(h, w2c[cc], ps[ri][i][cc]);
                }
        }

    #pragma unroll
    for (int off = 1; off < 16; off <<= 1)
        #pragma unroll
        for (int ri = 0; ri < 2; ++ri)
            #pragma unroll
            for (int i = 0; i < 4; ++i)
                #pragma unroll
                for (int cc = 0; cc < C_; ++cc)
                    ps[ri][i][cc] += __shfl_xor(ps[ri][i][cc], off, 64);

    if (tx == 0)
        #pragma unroll
        for (int ri = 0; ri < 2; ++ri)
            #pragma unroll
            for (int i = 0; i < 4; ++i) {
                const int m = m0 + ri * 64 + (ty << 2) + i;
                #pragma unroll
                for (int cc = 0; cc < C_; ++cc)
                    atomicAdd(&pot[m * C_ + cc], ps[ri][i][cc]);
            }
}

// =========================================================================
// Kernel 3: Viterbi via max-plus associative scan (verified).
// =========================================================================
__global__ __launch_bounds__(64) void viterbi_kernel(
    const float* __restrict__ pot, const float* __restrict__ trans,
    const int* __restrict__ mask, float* __restrict__ decoded,
    float* __restrict__ seqlen, float* __restrict__ chain_out)
{
    const int b = blockIdx.x;
    const int lane = threadIdx.x;

    __shared__ float pl[S_ * C_];
    __shared__ unsigned int bpk[S_];
    __shared__ unsigned int gseg[64];
    __shared__ int bt[64];
    __shared__ int dec_s[S_];
    __shared__ int s_last;

    const float* pb = pot + b * (S_ * C_);
    for (int i = lane; i < S_ * C_; i += 64) pl[i] = pb[i];

    int mcnt = 0;
    const int* mb = mask + b * S_;
    for (int i = lane; i < S_; i += 64) mcnt += (mb[i] != 0) ? 1 : 0;
    #pragma unroll
    for (int off = 32; off >= 1; off >>= 1) mcnt += __shfl_xor(mcnt, off, 64);

    if (b == 0 && lane < C_ * C_) chain_out[lane] = trans[lane];

    float tr[C_][C_];
    #pragma unroll
    for (int p = 0; p < C_; ++p)
        #pragma unroll
        for (int c = 0; c < C_; ++c) tr[p][c] = trans[p * C_ + c];

    __syncthreads();

    const float NEG = -1.0e30f;

    float G[C_][C_];
    #pragma unroll
    for (int c = 0; c < C_; ++c)
        #pragma unroll
        for (int p = 0; p < C_; ++p) G[c][p] = (c == p) ? 0.f : NEG;

    for (int j = 1; j <= 8; ++j) {
        const int t = 8 * lane + j;
        if (t < S_) {
            float ng[C_][C_];
            #pragma unroll
            for (int c = 0; c < C_; ++c) {
                const float pc = pl[t * C_ + c];
                #pragma unroll
                for (int p = 0; p < C_; ++p) {
                    float m = tr[0][c] + G[0][p];
                    #pragma unroll
                    for (int q = 1; q < C_; ++q)
                        m = fmaxf(m, tr[q][c] + G[q][p]);
                    ng[c][p] = m + pc;
                }
            }
            #pragma unroll
            for (int c = 0; c < C_; ++c)
                #pragma unroll
                for (int p = 0; p < C_; ++p) G[c][p] = ng[c][p];
        }
    }

    #pragma unroll
    for (int d = 1; d < 64; d <<= 1) {
        float Q[C_][C_];
        #pragma unroll
        for (int q = 0; q < C_; ++q)
            #pragma unroll
            for (int p = 0; p < C_; ++p) Q[q][p] = __shfl_up(G[q][p], d, 64);
        if (lane >= d) {
            float ng[C_][C_];
            #pragma unroll
            for (int c = 0; c < C_; ++c)
                #pragma unroll
                for (int p = 0; p < C_; ++p) {
                    float m = G[c][0] + Q[0][p];
                    #pragma unroll
                    for (int q = 1; q < C_; ++q)
                        m = fmaxf(m, G[c][q] + Q[q][p]);
                    ng[c][p] = m;
                }
            #pragma unroll
            for (int c = 0; c < C_; ++c)
                #pragma unroll
                for (int p = 0; p < C_; ++p) G[c][p] = ng[c][p];
        }
    }

    float a[C_];
    {
        float E[C_][C_];
        #pragma unroll
        for (int c = 0; c < C_; ++c)
            #pragma unroll
            for (int p = 0; p < C_; ++p) E[c][p] = __shfl_up(G[c][p], 1, 64);
        float a0[C_];
        #pragma unroll
        for (int c = 0; c < C_; ++c) a0[c] = pl[c];
        if (lane == 0) {
            #pragma unroll
            for (int c = 0; c < C_; ++c) a[c] = a0[c];
        } else {
            #pragma unroll
            for (int c = 0; c < C_; ++c) {
                float m = E[c][0] + a0[0];
                #pragma unroll
                for (int q = 1; q < C_; ++q) m = fmaxf(m, E[c][q] + a0[q]);
                a[c] = m;
            }
        }
    }

    for (int j = 1; j <= 8; ++j) {
        const int t = 8 * lane + j;
        if (t < S_) {
            unsigned int mpack = 0;
            float na[C_];
            #pragma unroll
            for (int c = 0; c < C_; ++c) {
                float best = a[0] + tr[0][c];
                int arg = 0;
                #pragma unroll
                for (int p = 1; p < C_; ++p) {
                    const float s = a[p] + tr[p][c];
                    if (s > best) { best = s; arg = p; }
                }
                mpack |= (unsigned int)arg << (3 * c);
                na[c] = best + pl[t * C_ + c];
            }
            bpk[t] = mpack;
            #pragma unroll
            for (int c = 0; c < C_; ++c) a[c] = na[c];
        }
    }

    if (lane == 63) {
        float best = a[0];
        int arg = 0;
        #pragma unroll
        for (int p = 1; p < C_; ++p)
            if (a[p] > best) { best = a[p]; arg = p; }
        s_last = arg;
    }
    if (lane == 0) bpk[0] = 0;
    __syncthreads();

    const int last = s_last;

    unsigned int g = 0u | (1u << 3) | (2u << 6) | (3u << 9) | (4u << 12);
    #pragma unroll
    for (int j = 7; j >= 0; --j) {
        const int t = 8 * lane + j;
        if (t >= 1) {
            const unsigned int m = bpk[t];
            unsigned int ng = 0;
            #pragma unroll
            for (int x = 0; x < C_; ++x) {
                const unsigned int gx = (g >> (3 * x)) & 7u;
                ng |= ((m >> (3 * gx)) & 7u) << (3 * x);
            }
            g = ng;
        }
    }
    gseg[lane] = g;
    __syncthreads();

    if (lane == 0) {
        int cur = last;
        for (int l = 63; l >= 0; --l) {
            bt[l] = cur;
            cur = (int)((gseg[l] >> (3 * cur)) & 7u);
        }
        seqlen[b] = (float)mcnt;
    }
    __syncthreads();

    {
        int tag = bt[lane];
        const int t0 = 8 * lane;
        dec_s[t0 + 7] = tag;
        #pragma unroll
        for (int t = t0 + 7; t >= t0 + 1; --t) {
            tag = (int)((bpk[t] >> (3 * tag)) & 7u);
            dec_s[t - 1] = tag;
        }
    }
    __syncthreads();

    float* db = decoded + b * S_;
    for (int i = lane; i < S_; i += 64) db[i] = (float)dec_s[i];
}

// =========================================================================
extern "C" void kernel_launch(void* const* d_in, const int* in_sizes, int n_in,
                              void* d_out, int out_size, void* d_ws, size_t ws_size,
                              hipStream_t stream) {
    const float* hs    = (const float*)d_in[0];
    const int*   mask  = (const int*)  d_in[1];
    const float* W1    = (const float*)d_in[2];
    const float* b1    = (const float*)d_in[3];
    const float* W2    = (const float*)d_in[4];
    const float* b2    = (const float*)d_in[5];
    const float* chain = (const float*)d_in[6];
    const float* lb    = (const float*)d_in[7];
    const float* rb    = (const float*)d_in[8];

    float* out      = (float*)d_out;
    float* decoded  = out;
    float* pot      = out + M_;
    float* seq      = out + M_ + M_ * C_;
    float* chainout = seq + B_;

    const size_t need = (size_t)W1T_ELEMS * 2 + (size_t)PART2_ELEMS * 4;   // ~2.5 MB

    if (ws_size >= need) {
        unsigned short* w1t = (unsigned short*)d_ws;
        float* part = (float*)(w1t + W1T_ELEMS);
        dim3 pgrid(H_ / 32, D_ / 32);
        prep_w1_kernel<<<pgrid, 256, 0, stream>>>(W1, w1t);
        gemm_half_kernel<<<512, 512, 0, stream>>>(hs, w1t, b1, W2, part);
        reduce_pot_kernel<<<(M_ * C_ + 255) / 256, 256, 0, stream>>>(
            part, b2, lb, rb, pot);
    } else {
        init_pot_kernel<<<(M_ * C_ + 255) / 256, 256, 0, stream>>>(b2, lb, rb, pot);
        dim3 grid(H_ / 128, M_ / 128);
        gemm_relu_pot_kernel<<<grid, 256, 0, stream>>>(hs, W1, b1, W2, pot);
    }

    viterbi_kernel<<<B_, 64, 0, stream>>>(pot, chain, mask, decoded, seq, chainout);
}